// Round 2
// baseline (1071.695 us; speedup 1.0000x reference)
//
#include <hip/hip_runtime.h>

// Problem constants (fixed by the reference)
#define N_SRNA  20000
#define N_MRNA  100000
#define FDIM    128
#define NE      1000000
#define NQ      500000
#define NDST_ALL (N_MRNA + N_SRNA)   // 120000 combined dst nodes (mrna first, then srna)

// ---------------------------------------------------------------------------
// CSR build: histogram -> 3-phase exclusive scan -> scatter
// ---------------------------------------------------------------------------

__global__ __launch_bounds__(256) void k_hist(const int* __restrict__ dst_sm,
                                              const int* __restrict__ dst_ms,
                                              int* __restrict__ deg_all) {
    int i = blockIdx.x * 256 + threadIdx.x;
    if (i < NE) {
        atomicAdd(&deg_all[dst_sm[i]], 1);
    } else if (i < 2 * NE) {
        atomicAdd(&deg_all[N_MRNA + dst_ms[i - NE]], 1);
    }
}

__global__ __launch_bounds__(1024) void k_scan_reduce(const int* __restrict__ deg,
                                                      int* __restrict__ bsum, int n) {
    int i = blockIdx.x * 1024 + threadIdx.x;
    int v = (i < n) ? deg[i] : 0;
    for (int off = 32; off; off >>= 1) v += __shfl_down(v, off);
    __shared__ int wsum[16];
    int lane = threadIdx.x & 63, wid = threadIdx.x >> 6;
    if (lane == 0) wsum[wid] = v;
    __syncthreads();
    if (threadIdx.x == 0) {
        int s = 0;
        for (int j = 0; j < 16; ++j) s += wsum[j];
        bsum[blockIdx.x] = s;
    }
}

// Single block: exclusive-scan the per-block sums in place; write grand total to ptr_end.
__global__ __launch_bounds__(256) void k_scan_mid(int* __restrict__ bsum, int nb,
                                                  int* __restrict__ ptr_end) {
    __shared__ int b[256];
    int t = threadIdx.x;
    int v = (t < nb) ? bsum[t] : 0;
    b[t] = v;
    __syncthreads();
    for (int off = 1; off < 256; off <<= 1) {
        int x = (t >= off) ? b[t - off] : 0;
        __syncthreads();
        b[t] += x;
        __syncthreads();
    }
    if (t < nb) bsum[t] = b[t] - v;     // exclusive
    if (t == 255) *ptr_end = b[255];    // total (= 2*NE)
}

__global__ __launch_bounds__(1024) void k_scan_final(const int* __restrict__ deg,
                                                     const int* __restrict__ bsum,
                                                     int* __restrict__ ptr,
                                                     int* __restrict__ cur, int n) {
    int t = threadIdx.x;
    int i = blockIdx.x * 1024 + t;
    int v = (i < n) ? deg[i] : 0;
    int lane = t & 63, wid = t >> 6;
    int incl = v;
    for (int off = 1; off < 64; off <<= 1) {
        int x = __shfl_up(incl, off);
        if (lane >= off) incl += x;
    }
    __shared__ int wsum[16];
    if (lane == 63) wsum[wid] = incl;
    __syncthreads();
    if (t == 0) {
        int run = 0;
        for (int j = 0; j < 16; ++j) { int x = wsum[j]; wsum[j] = run; run += x; }
    }
    __syncthreads();
    int ex = incl - v + wsum[wid] + bsum[blockIdx.x];
    if (i < n) { ptr[i] = ex; cur[i] = ex; }
}

__global__ __launch_bounds__(256) void k_scatter(const int* __restrict__ src_sm,
                                                 const int* __restrict__ dst_sm,
                                                 const int* __restrict__ src_ms,
                                                 const int* __restrict__ dst_ms,
                                                 int* __restrict__ cur,
                                                 int* __restrict__ col) {
    int i = blockIdx.x * 256 + threadIdx.x;
    if (i < NE) {
        int p = atomicAdd(&cur[dst_sm[i]], 1);
        col[p] = src_sm[i];
    } else if (i < 2 * NE) {
        int j = i - NE;
        int p = atomicAdd(&cur[N_MRNA + dst_ms[j]], 1);
        col[p] = src_ms[j];
    }
}

// ---------------------------------------------------------------------------
// Segment mean: one wave per dst row; lane holds 2 features (float2).
// ---------------------------------------------------------------------------
__global__ __launch_bounds__(256) void k_seg_mean(const float* __restrict__ xsrc,
                                                  const int* __restrict__ rowptr,
                                                  const int* __restrict__ cols,
                                                  float* __restrict__ outm, int ndst) {
    int wave = (blockIdx.x * 256 + threadIdx.x) >> 6;
    int lane = threadIdx.x & 63;
    if (wave >= ndst) return;
    int beg = rowptr[wave], end = rowptr[wave + 1];
    float2 a0 = {0.f, 0.f}, a1 = {0.f, 0.f}, a2 = {0.f, 0.f}, a3 = {0.f, 0.f};
    int e = beg;
    for (; e + 4 <= end; e += 4) {
        int s0 = cols[e], s1 = cols[e + 1], s2 = cols[e + 2], s3 = cols[e + 3];
        float2 v0 = ((const float2*)(xsrc + (size_t)s0 * FDIM))[lane];
        float2 v1 = ((const float2*)(xsrc + (size_t)s1 * FDIM))[lane];
        float2 v2 = ((const float2*)(xsrc + (size_t)s2 * FDIM))[lane];
        float2 v3 = ((const float2*)(xsrc + (size_t)s3 * FDIM))[lane];
        a0.x += v0.x; a0.y += v0.y;
        a1.x += v1.x; a1.y += v1.y;
        a2.x += v2.x; a2.y += v2.y;
        a3.x += v3.x; a3.y += v3.y;
    }
    for (; e < end; ++e) {
        int s = cols[e];
        float2 v = ((const float2*)(xsrc + (size_t)s * FDIM))[lane];
        a0.x += v.x; a0.y += v.y;
    }
    float inv = 1.0f / fmaxf((float)(end - beg), 1.0f);
    float2 o;
    o.x = (a0.x + a1.x + a2.x + a3.x) * inv;
    o.y = (a0.y + a1.y + a2.y + a3.y) * inv;
    ((float2*)(outm + (size_t)wave * FDIM))[lane] = o;
}

// ---------------------------------------------------------------------------
// Dual GEMM: out[n,128] = mean @ Wl + bias + xd @ Wr, optional ReLU.
// 64-row tiles in LDS (padded to 132 to make the 4-row broadcast read 2-way),
// W streamed from L1/L2. Safe for out == mean (tile staged to LDS pre-store).
// ---------------------------------------------------------------------------
template <bool RELU>
__global__ __launch_bounds__(256) void k_gemm_dual(const float* __restrict__ mean,
                                                   const float* __restrict__ xd,
                                                   const float* __restrict__ Wl,
                                                   const float* __restrict__ Wr,
                                                   const float* __restrict__ bias,
                                                   float* __restrict__ out, int n) {
    __shared__ float sA[64][132];
    __shared__ float sB[64][132];
    const int t = threadIdx.x;
    const int r0 = blockIdx.x * 64;
    for (int idx = t; idx < 64 * 32; idx += 256) {
        int r = idx >> 5, c = (idx & 31) * 4;
        int gr = r0 + r;
        float4 va, vb;
        if (gr < n) {
            va = *(const float4*)(mean + (size_t)gr * FDIM + c);
            vb = *(const float4*)(xd + (size_t)gr * FDIM + c);
        } else {
            va = make_float4(0.f, 0.f, 0.f, 0.f);
            vb = va;
        }
        *(float4*)&sA[r][c] = va;
        *(float4*)&sB[r][c] = vb;
    }
    __syncthreads();

    const int c0 = (t & 15) * 8;
    const int rr = (t >> 4) * 4;
    float acc[4][8];
#pragma unroll
    for (int r = 0; r < 4; ++r)
#pragma unroll
        for (int c = 0; c < 8; ++c) acc[r][c] = 0.f;

#pragma unroll 2
    for (int k = 0; k < 128; ++k) {
        const float4 wl0 = *(const float4*)(Wl + (k << 7) + c0);
        const float4 wl1 = *(const float4*)(Wl + (k << 7) + c0 + 4);
        const float4 wr0 = *(const float4*)(Wr + (k << 7) + c0);
        const float4 wr1 = *(const float4*)(Wr + (k << 7) + c0 + 4);
#pragma unroll
        for (int r = 0; r < 4; ++r) {
            const float a = sA[rr + r][k];
            const float b = sB[rr + r][k];
            acc[r][0] = fmaf(a, wl0.x, acc[r][0]); acc[r][0] = fmaf(b, wr0.x, acc[r][0]);
            acc[r][1] = fmaf(a, wl0.y, acc[r][1]); acc[r][1] = fmaf(b, wr0.y, acc[r][1]);
            acc[r][2] = fmaf(a, wl0.z, acc[r][2]); acc[r][2] = fmaf(b, wr0.z, acc[r][2]);
            acc[r][3] = fmaf(a, wl0.w, acc[r][3]); acc[r][3] = fmaf(b, wr0.w, acc[r][3]);
            acc[r][4] = fmaf(a, wl1.x, acc[r][4]); acc[r][4] = fmaf(b, wr1.x, acc[r][4]);
            acc[r][5] = fmaf(a, wl1.y, acc[r][5]); acc[r][5] = fmaf(b, wr1.y, acc[r][5]);
            acc[r][6] = fmaf(a, wl1.z, acc[r][6]); acc[r][6] = fmaf(b, wr1.z, acc[r][6]);
            acc[r][7] = fmaf(a, wl1.w, acc[r][7]); acc[r][7] = fmaf(b, wr1.w, acc[r][7]);
        }
    }

    const float4 b0 = *(const float4*)(bias + c0);
    const float4 b1 = *(const float4*)(bias + c0 + 4);
    const float bv[8] = {b0.x, b0.y, b0.z, b0.w, b1.x, b1.y, b1.z, b1.w};
#pragma unroll
    for (int r = 0; r < 4; ++r) {
        int row = r0 + rr + r;
        if (row < n) {
            float o[8];
#pragma unroll
            for (int c = 0; c < 8; ++c) {
                float v = acc[r][c] + bv[c];
                o[c] = RELU ? fmaxf(v, 0.f) : v;
            }
            *(float4*)(out + (size_t)row * FDIM + c0)     = make_float4(o[0], o[1], o[2], o[3]);
            *(float4*)(out + (size_t)row * FDIM + c0 + 4) = make_float4(o[4], o[5], o[6], o[7]);
        }
    }
}

// ---------------------------------------------------------------------------
// Decoder: out[q] = dot(zS[row[q]], zM[col[q]]) ; wave per query.
// ---------------------------------------------------------------------------
__global__ __launch_bounds__(256) void k_decoder(const float* __restrict__ zS,
                                                 const float* __restrict__ zM,
                                                 const int* __restrict__ rows,
                                                 const int* __restrict__ cols,
                                                 float* __restrict__ out) {
    int w = (blockIdx.x * 256 + threadIdx.x) >> 6;
    int lane = threadIdx.x & 63;
    if (w >= NQ) return;
    int r = rows[w], c = cols[w];
    float2 va = ((const float2*)(zS + (size_t)r * FDIM))[lane];
    float2 vb = ((const float2*)(zM + (size_t)c * FDIM))[lane];
    float s = va.x * vb.x + va.y * vb.y;
    for (int off = 32; off; off >>= 1) s += __shfl_down(s, off);
    if (lane == 0) out[w] = s;
}

// ---------------------------------------------------------------------------
// Launch
// ---------------------------------------------------------------------------
extern "C" void kernel_launch(void* const* d_in, const int* in_sizes, int n_in,
                              void* d_out, int out_size, void* d_ws, size_t ws_size,
                              hipStream_t stream) {
    const float* x_srna = (const float*)d_in[0];
    const float* x_mrna = (const float*)d_in[1];
    const int* src_sm = (const int*)d_in[2];
    const int* dst_sm = (const int*)d_in[3];
    const int* src_ms = (const int*)d_in[4];
    const int* dst_ms = (const int*)d_in[5];
    const int* lbl_row = (const int*)d_in[6];
    const int* lbl_col = (const int*)d_in[7];
    const float* W1l_sm = (const float*)d_in[8];
    const float* W1r_sm = (const float*)d_in[9];
    const float* W1l_ms = (const float*)d_in[10];
    const float* W1r_ms = (const float*)d_in[11];
    const float* W2l_sm = (const float*)d_in[12];
    const float* W2r_sm = (const float*)d_in[13];
    const float* W2l_ms = (const float*)d_in[14];
    const float* W2r_ms = (const float*)d_in[15];
    const float* b1_sm = (const float*)d_in[16];
    const float* b1_ms = (const float*)d_in[17];
    const float* b2_sm = (const float*)d_in[18];
    const float* b2_ms = (const float*)d_in[19];
    float* out = (float*)d_out;

    // Workspace layout (all 16B-aligned)
    char* ws = (char*)d_ws;
    float* meanM = (float*)(ws + 0);                       //  51,200,000 B
    float* meanS = (float*)(ws + 51200000);                //  10,240,000 B
    float* hM    = (float*)(ws + 61440000);                //  51,200,000 B
    float* hS    = (float*)(ws + 112640000);               //  10,240,000 B
    int* deg_all = (int*)(ws + 122880000);                 //     480,000 B
    int* ptr_all = (int*)(ws + 123360000);                 //     480,016 B (120001 ints)
    int* cur_all = (int*)(ws + 123840016);                 //     480,000 B
    int* col_all = (int*)(ws + 124320016);                 //   8,000,000 B
    int* bsum    = (int*)(ws + 132320016);                 //       1,024 B
    // total: ~132.3 MB

    // --- CSR build ---
    hipMemsetAsync(deg_all, 0, NDST_ALL * sizeof(int), stream);
    k_hist<<<(2 * NE + 255) / 256, 256, 0, stream>>>(dst_sm, dst_ms, deg_all);
    const int nscan = (NDST_ALL + 1023) / 1024;            // 118
    k_scan_reduce<<<nscan, 1024, 0, stream>>>(deg_all, bsum, NDST_ALL);
    k_scan_mid<<<1, 256, 0, stream>>>(bsum, nscan, &ptr_all[NDST_ALL]);
    k_scan_final<<<nscan, 1024, 0, stream>>>(deg_all, bsum, ptr_all, cur_all, NDST_ALL);
    k_scatter<<<(2 * NE + 255) / 256, 256, 0, stream>>>(src_sm, dst_sm, src_ms, dst_ms,
                                                        cur_all, col_all);

    // --- Layer 1 ---
    k_seg_mean<<<(N_MRNA + 3) / 4, 256, 0, stream>>>(x_srna, ptr_all, col_all, meanM, N_MRNA);
    k_seg_mean<<<(N_SRNA + 3) / 4, 256, 0, stream>>>(x_mrna, ptr_all + N_MRNA, col_all, meanS, N_SRNA);
    k_gemm_dual<true><<<(N_MRNA + 63) / 64, 256, 0, stream>>>(meanM, x_mrna, W1l_sm, W1r_sm,
                                                              b1_sm, hM, N_MRNA);
    k_gemm_dual<true><<<(N_SRNA + 63) / 64, 256, 0, stream>>>(meanS, x_srna, W1l_ms, W1r_ms,
                                                              b1_ms, hS, N_SRNA);

    // --- Layer 2 (z written in-place over mean buffers) ---
    k_seg_mean<<<(N_MRNA + 3) / 4, 256, 0, stream>>>(hS, ptr_all, col_all, meanM, N_MRNA);
    k_seg_mean<<<(N_SRNA + 3) / 4, 256, 0, stream>>>(hM, ptr_all + N_MRNA, col_all, meanS, N_SRNA);
    k_gemm_dual<false><<<(N_MRNA + 63) / 64, 256, 0, stream>>>(meanM, hM, W2l_sm, W2r_sm,
                                                               b2_sm, meanM, N_MRNA);
    k_gemm_dual<false><<<(N_SRNA + 63) / 64, 256, 0, stream>>>(meanS, hS, W2l_ms, W2r_ms,
                                                               b2_ms, meanS, N_SRNA);

    // --- Decoder ---
    k_decoder<<<(NQ + 3) / 4, 256, 0, stream>>>(meanS, meanM, lbl_row, lbl_col, out);
}

// Round 3
// 740.371 us; speedup vs baseline: 1.4475x; 1.4475x over previous
//
#include <hip/hip_runtime.h>

// Problem constants (fixed by the reference)
#define N_SRNA  20000
#define N_MRNA  100000
#define FDIM    128
#define NE      1000000
#define NQ      500000
#define NDST_ALL (N_MRNA + N_SRNA)   // 120000 combined dst nodes (mrna first, then srna)

typedef __attribute__((ext_vector_type(8))) short bf16x8;
typedef __attribute__((ext_vector_type(4))) float f32x4;

__device__ __forceinline__ unsigned short f2bf(float f) {
    unsigned int u = __float_as_uint(f);
    unsigned int r = (u + 0x7fffu + ((u >> 16) & 1u)) >> 16;   // RNE
    return (unsigned short)r;
}
__device__ __forceinline__ float bf2f(unsigned short h) {
    return __uint_as_float((unsigned int)h << 16);
}

// ---------------------------------------------------------------------------
// CSR build: histogram -> 3-phase exclusive scan -> scatter (unchanged)
// ---------------------------------------------------------------------------

__global__ __launch_bounds__(256) void k_hist(const int* __restrict__ dst_sm,
                                              const int* __restrict__ dst_ms,
                                              int* __restrict__ deg_all) {
    int i = blockIdx.x * 256 + threadIdx.x;
    if (i < NE) {
        atomicAdd(&deg_all[dst_sm[i]], 1);
    } else if (i < 2 * NE) {
        atomicAdd(&deg_all[N_MRNA + dst_ms[i - NE]], 1);
    }
}

__global__ __launch_bounds__(1024) void k_scan_reduce(const int* __restrict__ deg,
                                                      int* __restrict__ bsum, int n) {
    int i = blockIdx.x * 1024 + threadIdx.x;
    int v = (i < n) ? deg[i] : 0;
    for (int off = 32; off; off >>= 1) v += __shfl_down(v, off);
    __shared__ int wsum[16];
    int lane = threadIdx.x & 63, wid = threadIdx.x >> 6;
    if (lane == 0) wsum[wid] = v;
    __syncthreads();
    if (threadIdx.x == 0) {
        int s = 0;
        for (int j = 0; j < 16; ++j) s += wsum[j];
        bsum[blockIdx.x] = s;
    }
}

__global__ __launch_bounds__(256) void k_scan_mid(int* __restrict__ bsum, int nb,
                                                  int* __restrict__ ptr_end) {
    __shared__ int b[256];
    int t = threadIdx.x;
    int v = (t < nb) ? bsum[t] : 0;
    b[t] = v;
    __syncthreads();
    for (int off = 1; off < 256; off <<= 1) {
        int x = (t >= off) ? b[t - off] : 0;
        __syncthreads();
        b[t] += x;
        __syncthreads();
    }
    if (t < nb) bsum[t] = b[t] - v;     // exclusive
    if (t == 255) *ptr_end = b[255];    // total (= 2*NE)
}

__global__ __launch_bounds__(1024) void k_scan_final(const int* __restrict__ deg,
                                                     const int* __restrict__ bsum,
                                                     int* __restrict__ ptr,
                                                     int* __restrict__ cur, int n) {
    int t = threadIdx.x;
    int i = blockIdx.x * 1024 + t;
    int v = (i < n) ? deg[i] : 0;
    int lane = t & 63, wid = t >> 6;
    int incl = v;
    for (int off = 1; off < 64; off <<= 1) {
        int x = __shfl_up(incl, off);
        if (lane >= off) incl += x;
    }
    __shared__ int wsum[16];
    if (lane == 63) wsum[wid] = incl;
    __syncthreads();
    if (t == 0) {
        int run = 0;
        for (int j = 0; j < 16; ++j) { int x = wsum[j]; wsum[j] = run; run += x; }
    }
    __syncthreads();
    int ex = incl - v + wsum[wid] + bsum[blockIdx.x];
    if (i < n) { ptr[i] = ex; cur[i] = ex; }
}

__global__ __launch_bounds__(256) void k_scatter(const int* __restrict__ src_sm,
                                                 const int* __restrict__ dst_sm,
                                                 const int* __restrict__ src_ms,
                                                 const int* __restrict__ dst_ms,
                                                 int* __restrict__ cur,
                                                 int* __restrict__ col) {
    int i = blockIdx.x * 256 + threadIdx.x;
    if (i < NE) {
        int p = atomicAdd(&cur[dst_sm[i]], 1);
        col[p] = src_sm[i];
    } else if (i < 2 * NE) {
        int j = i - NE;
        int p = atomicAdd(&cur[N_MRNA + dst_ms[j]], 1);
        col[p] = src_ms[j];
    }
}

// ---------------------------------------------------------------------------
// fp32 -> bf16 conversion (vectorized, grid-stride)
// ---------------------------------------------------------------------------
__global__ __launch_bounds__(256) void k_cvt_bf(const float* __restrict__ src,
                                                unsigned short* __restrict__ dst, int n4) {
    int i = blockIdx.x * 256 + threadIdx.x;
    int stride = gridDim.x * 256;
    for (; i < n4; i += stride) {
        float4 v = ((const float4*)src)[i];
        unsigned int p0 = (unsigned int)f2bf(v.x) | ((unsigned int)f2bf(v.y) << 16);
        unsigned int p1 = (unsigned int)f2bf(v.z) | ((unsigned int)f2bf(v.w) << 16);
        ((uint2*)dst)[i] = make_uint2(p0, p1);
    }
}

// Build Wt[c][k] = bf16( k<128 ? Wl[k][c] : Wr[k-128][c] ), c in [0,128), k in [0,256)
__global__ __launch_bounds__(256) void k_build_wt(const float* __restrict__ Wl,
                                                  const float* __restrict__ Wr,
                                                  unsigned short* __restrict__ Wt) {
    int tid = blockIdx.x * 256 + threadIdx.x;   // 32768 threads
    int c = tid & 127, k = tid >> 7;
    float v = (k < 128) ? Wl[k * 128 + c] : Wr[(k - 128) * 128 + c];
    Wt[c * 256 + k] = f2bf(v);
}

// ---------------------------------------------------------------------------
// Segment mean over bf16 rows: one wave per dst row; lane holds 2 features.
// fp32 accumulate, bf16 output.
// ---------------------------------------------------------------------------
__global__ __launch_bounds__(256) void k_seg_mean_bf(const unsigned short* __restrict__ xsrc,
                                                     const int* __restrict__ rowptr,
                                                     const int* __restrict__ cols,
                                                     unsigned short* __restrict__ outm,
                                                     int ndst) {
    int wave = (blockIdx.x * 256 + threadIdx.x) >> 6;
    int lane = threadIdx.x & 63;
    if (wave >= ndst) return;
    int beg = rowptr[wave], end = rowptr[wave + 1];
    float a0x = 0.f, a0y = 0.f, a1x = 0.f, a1y = 0.f;
    float a2x = 0.f, a2y = 0.f, a3x = 0.f, a3y = 0.f;
    int e = beg;
    for (; e + 4 <= end; e += 4) {
        int s0 = cols[e], s1 = cols[e + 1], s2 = cols[e + 2], s3 = cols[e + 3];
        unsigned int v0 = ((const unsigned int*)(xsrc + (size_t)s0 * FDIM))[lane];
        unsigned int v1 = ((const unsigned int*)(xsrc + (size_t)s1 * FDIM))[lane];
        unsigned int v2 = ((const unsigned int*)(xsrc + (size_t)s2 * FDIM))[lane];
        unsigned int v3 = ((const unsigned int*)(xsrc + (size_t)s3 * FDIM))[lane];
        a0x += bf2f((unsigned short)v0); a0y += bf2f((unsigned short)(v0 >> 16));
        a1x += bf2f((unsigned short)v1); a1y += bf2f((unsigned short)(v1 >> 16));
        a2x += bf2f((unsigned short)v2); a2y += bf2f((unsigned short)(v2 >> 16));
        a3x += bf2f((unsigned short)v3); a3y += bf2f((unsigned short)(v3 >> 16));
    }
    for (; e < end; ++e) {
        unsigned int v = ((const unsigned int*)(xsrc + (size_t)cols[e] * FDIM))[lane];
        a0x += bf2f((unsigned short)v); a0y += bf2f((unsigned short)(v >> 16));
    }
    float inv = 1.0f / fmaxf((float)(end - beg), 1.0f);
    float ox = (a0x + a1x + a2x + a3x) * inv;
    float oy = (a0y + a1y + a2y + a3y) * inv;
    unsigned int packed = (unsigned int)f2bf(ox) | ((unsigned int)f2bf(oy) << 16);
    ((unsigned int*)(outm + (size_t)wave * FDIM))[lane] = packed;
}

// ---------------------------------------------------------------------------
// MFMA GEMM: out[n][128] = [A0 | A1] @ W (K=256 concat) + bias, optional ReLU.
// A0 = mean_bf [n][128] (k 0..127), A1 = xd_bf [n][128] (k 128..255).
// Wt[c][k] (= W[k][c]) staged to LDS with XOR swizzle. Block 128x128, 4 waves
// of 64x64 (4x4 frags of 16x16x32). In-place out==A0 is safe (all A reads of a
// block finish before its epilogue writes; blocks own disjoint rows).
// ---------------------------------------------------------------------------
template <bool RELU>
__global__ __launch_bounds__(256, 2) void k_gemm_mfma(const unsigned short* __restrict__ A0,
                                                      const unsigned short* __restrict__ A1,
                                                      const unsigned short* __restrict__ Wt,
                                                      const float* __restrict__ bias,
                                                      unsigned short* __restrict__ out,
                                                      int n) {
    __shared__ uint4 smem4[4352];            // 69632 B: 64KB W stage, reused as 4x17408B epilogue
    char* smem = (char*)smem4;

    const int t = threadIdx.x;
    // Stage Wt -> LDS, XOR-swizzled: row c at c*512, 16B-slot index ^= (c&7)
#pragma unroll
    for (int i = 0; i < 16; ++i) {
        int j = i * 256 + t;                 // 4096 chunks of 16B
        int byteo = j << 4;
        int c = byteo >> 9;
        int off = byteo & 511;
        int swz = off ^ ((c & 7) << 4);
        uint4 v = ((const uint4*)Wt)[j];
        *(uint4*)(smem + c * 512 + swz) = v;
    }
    __syncthreads();

    const int w = t >> 6, l = t & 63;
    const int wr = w >> 1, wc = w & 1;       // 2x2 wave grid
    const int rowbase = blockIdx.x * 128 + wr * 64;
    const int colbase = wc * 64;
    const int lr = l & 15;                   // fragment row/col selector
    const int lk = (l >> 4) * 8;             // fragment k selector (elements)

    f32x4 acc[4][4];
#pragma unroll
    for (int a = 0; a < 4; ++a)
#pragma unroll
        for (int b = 0; b < 4; ++b)
#pragma unroll
            for (int e = 0; e < 4; ++e) acc[a][b][e] = 0.f;

    bf16x8 az;
#pragma unroll
    for (int e = 0; e < 8; ++e) az[e] = 0;

#pragma unroll
    for (int s = 0; s < 8; ++s) {
        const unsigned short* Abuf = (s < 4) ? A0 : A1;
        const int kk = (s & 3) * 32 + lk;    // 0..127 within buffer
        bf16x8 afr[4];
#pragma unroll
        for (int af = 0; af < 4; ++af) {
            int row = rowbase + af * 16 + lr;
            afr[af] = (row < n) ? *(const bf16x8*)(Abuf + (size_t)row * FDIM + kk) : az;
        }
        bf16x8 bfr[4];
#pragma unroll
        for (int bf = 0; bf < 4; ++bf) {
            int c = colbase + bf * 16 + lr;
            int off = s * 64 + lk * 2;       // byte offset of k within Wt row
            int swz = off ^ ((c & 7) << 4);
            bfr[bf] = *(const bf16x8*)(smem + c * 512 + swz);
        }
#pragma unroll
        for (int af = 0; af < 4; ++af)
#pragma unroll
            for (int bf = 0; bf < 4; ++bf)
                acc[af][bf] = __builtin_amdgcn_mfma_f32_16x16x32_bf16(afr[af], bfr[bf],
                                                                      acc[af][bf], 0, 0, 0);
    }

    __syncthreads();                         // all waves done reading W; reuse LDS
    float* sD = (float*)(smem + w * 17408);  // 64 x 68 fp32 per wave

#pragma unroll
    for (int af = 0; af < 4; ++af)
#pragma unroll
        for (int bf = 0; bf < 4; ++bf)
#pragma unroll
            for (int r = 0; r < 4; ++r)
                sD[(af * 16 + (l >> 4) * 4 + r) * 68 + bf * 16 + lr] = acc[af][bf][r];

    // readback: lane handles 8 consecutive cols of one row per iter
#pragma unroll
    for (int j = 0; j < 8; ++j) {
        int flat = j * 512 + l * 8;
        int row = flat >> 6;                 // 0..63
        int c0 = flat & 63;
        int grow = rowbase + row;
        if (grow >= n) continue;
        float4 v0 = *(float4*)(&sD[row * 68 + c0]);
        float4 v1 = *(float4*)(&sD[row * 68 + c0 + 4]);
        int gc = colbase + c0;
        float4 b0 = *(const float4*)(bias + gc);
        float4 b1 = *(const float4*)(bias + gc + 4);
        float o[8] = {v0.x + b0.x, v0.y + b0.y, v0.z + b0.z, v0.w + b0.w,
                      v1.x + b1.x, v1.y + b1.y, v1.z + b1.z, v1.w + b1.w};
        if (RELU) {
#pragma unroll
            for (int e = 0; e < 8; ++e) o[e] = fmaxf(o[e], 0.f);
        }
        uint4 pv;
        pv.x = (unsigned int)f2bf(o[0]) | ((unsigned int)f2bf(o[1]) << 16);
        pv.y = (unsigned int)f2bf(o[2]) | ((unsigned int)f2bf(o[3]) << 16);
        pv.z = (unsigned int)f2bf(o[4]) | ((unsigned int)f2bf(o[5]) << 16);
        pv.w = (unsigned int)f2bf(o[6]) | ((unsigned int)f2bf(o[7]) << 16);
        *(uint4*)(out + (size_t)grow * FDIM + gc) = pv;
    }
}

// ---------------------------------------------------------------------------
// Decoder: out[q] = dot(zS[row[q]], zM[col[q]]) over bf16 rows; wave per query.
// ---------------------------------------------------------------------------
__global__ __launch_bounds__(256) void k_decoder_bf(const unsigned short* __restrict__ zS,
                                                    const unsigned short* __restrict__ zM,
                                                    const int* __restrict__ rows,
                                                    const int* __restrict__ cols,
                                                    float* __restrict__ out) {
    int w = (blockIdx.x * 256 + threadIdx.x) >> 6;
    int lane = threadIdx.x & 63;
    if (w >= NQ) return;
    int r = rows[w], c = cols[w];
    unsigned int va = ((const unsigned int*)(zS + (size_t)r * FDIM))[lane];
    unsigned int vb = ((const unsigned int*)(zM + (size_t)c * FDIM))[lane];
    float s = bf2f((unsigned short)va) * bf2f((unsigned short)vb) +
              bf2f((unsigned short)(va >> 16)) * bf2f((unsigned short)(vb >> 16));
    for (int off = 32; off; off >>= 1) s += __shfl_down(s, off);
    if (lane == 0) out[w] = s;
}

// ---------------------------------------------------------------------------
// Launch
// ---------------------------------------------------------------------------
extern "C" void kernel_launch(void* const* d_in, const int* in_sizes, int n_in,
                              void* d_out, int out_size, void* d_ws, size_t ws_size,
                              hipStream_t stream) {
    const float* x_srna = (const float*)d_in[0];
    const float* x_mrna = (const float*)d_in[1];
    const int* src_sm = (const int*)d_in[2];
    const int* dst_sm = (const int*)d_in[3];
    const int* src_ms = (const int*)d_in[4];
    const int* dst_ms = (const int*)d_in[5];
    const int* lbl_row = (const int*)d_in[6];
    const int* lbl_col = (const int*)d_in[7];
    const float* W1l_sm = (const float*)d_in[8];
    const float* W1r_sm = (const float*)d_in[9];
    const float* W1l_ms = (const float*)d_in[10];
    const float* W1r_ms = (const float*)d_in[11];
    const float* W2l_sm = (const float*)d_in[12];
    const float* W2r_sm = (const float*)d_in[13];
    const float* W2l_ms = (const float*)d_in[14];
    const float* W2r_ms = (const float*)d_in[15];
    const float* b1_sm = (const float*)d_in[16];
    const float* b1_ms = (const float*)d_in[17];
    const float* b2_sm = (const float*)d_in[18];
    const float* b2_ms = (const float*)d_in[19];
    float* out = (float*)d_out;

    // Workspace layout (16B aligned)
    char* ws = (char*)d_ws;
    unsigned short* xS_bf   = (unsigned short*)(ws + 0);          //  5,120,000
    unsigned short* xM_bf   = (unsigned short*)(ws + 5120000);    // 25,600,000
    unsigned short* meanM   = (unsigned short*)(ws + 30720000);   // 25,600,000 (becomes zM)
    unsigned short* meanS   = (unsigned short*)(ws + 56320000);   //  5,120,000 (becomes zS)
    unsigned short* hM_bf   = (unsigned short*)(ws + 61440000);   // 25,600,000
    unsigned short* hS_bf   = (unsigned short*)(ws + 87040000);   //  5,120,000
    unsigned short* Wt1sm   = (unsigned short*)(ws + 92160000);   //     65,536
    unsigned short* Wt1ms   = (unsigned short*)(ws + 92225536);   //     65,536
    unsigned short* Wt2sm   = (unsigned short*)(ws + 92291072);   //     65,536
    unsigned short* Wt2ms   = (unsigned short*)(ws + 92356608);   //     65,536
    int* deg_all = (int*)(ws + 92422144);                         //    480,000
    int* ptr_all = (int*)(ws + 92902144);                         //    480,016
    int* cur_all = (int*)(ws + 93382160);                         //    480,000
    int* col_all = (int*)(ws + 93862160);                         //  8,000,000
    int* bsum    = (int*)(ws + 101862160);                        //      1,024
    // total ~101.9 MB

    // --- dtype prep (independent of CSR) ---
    k_cvt_bf<<<2048, 256, 0, stream>>>(x_srna, xS_bf, N_SRNA * FDIM / 4);
    k_cvt_bf<<<2048, 256, 0, stream>>>(x_mrna, xM_bf, N_MRNA * FDIM / 4);
    k_build_wt<<<128, 256, 0, stream>>>(W1l_sm, W1r_sm, Wt1sm);
    k_build_wt<<<128, 256, 0, stream>>>(W1l_ms, W1r_ms, Wt1ms);
    k_build_wt<<<128, 256, 0, stream>>>(W2l_sm, W2r_sm, Wt2sm);
    k_build_wt<<<128, 256, 0, stream>>>(W2l_ms, W2r_ms, Wt2ms);

    // --- CSR build ---
    hipMemsetAsync(deg_all, 0, NDST_ALL * sizeof(int), stream);
    k_hist<<<(2 * NE + 255) / 256, 256, 0, stream>>>(dst_sm, dst_ms, deg_all);
    const int nscan = (NDST_ALL + 1023) / 1024;            // 118
    k_scan_reduce<<<nscan, 1024, 0, stream>>>(deg_all, bsum, NDST_ALL);
    k_scan_mid<<<1, 256, 0, stream>>>(bsum, nscan, &ptr_all[NDST_ALL]);
    k_scan_final<<<nscan, 1024, 0, stream>>>(deg_all, bsum, ptr_all, cur_all, NDST_ALL);
    k_scatter<<<(2 * NE + 255) / 256, 256, 0, stream>>>(src_sm, dst_sm, src_ms, dst_ms,
                                                        cur_all, col_all);

    // --- Layer 1 ---
    k_seg_mean_bf<<<(N_MRNA + 3) / 4, 256, 0, stream>>>(xS_bf, ptr_all, col_all, meanM, N_MRNA);
    k_seg_mean_bf<<<(N_SRNA + 3) / 4, 256, 0, stream>>>(xM_bf, ptr_all + N_MRNA, col_all, meanS, N_SRNA);
    k_gemm_mfma<true><<<(N_MRNA + 127) / 128, 256, 0, stream>>>(meanM, xM_bf, Wt1sm, b1_sm,
                                                                hM_bf, N_MRNA);
    k_gemm_mfma<true><<<(N_SRNA + 127) / 128, 256, 0, stream>>>(meanS, xS_bf, Wt1ms, b1_ms,
                                                                hS_bf, N_SRNA);

    // --- Layer 2 (z overwrites mean buffers in place) ---
    k_seg_mean_bf<<<(N_MRNA + 3) / 4, 256, 0, stream>>>(hS_bf, ptr_all, col_all, meanM, N_MRNA);
    k_seg_mean_bf<<<(N_SRNA + 3) / 4, 256, 0, stream>>>(hM_bf, ptr_all + N_MRNA, col_all, meanS, N_SRNA);
    k_gemm_mfma<false><<<(N_MRNA + 127) / 128, 256, 0, stream>>>(meanM, hM_bf, Wt2sm, b2_sm,
                                                                 meanM, N_MRNA);
    k_gemm_mfma<false><<<(N_SRNA + 127) / 128, 256, 0, stream>>>(meanS, hS_bf, Wt2ms, b2_ms,
                                                                 meanS, N_SRNA);

    // --- Decoder ---
    k_decoder_bf<<<(NQ + 3) / 4, 256, 0, stream>>>(meanS, meanM, lbl_row, lbl_col, out);
}

// Round 4
// 544.084 us; speedup vs baseline: 1.9697x; 1.3608x over previous
//
#include <hip/hip_runtime.h>

// Problem constants (fixed by the reference)
#define N_SRNA  20000
#define N_MRNA  100000
#define FDIM    128
#define NE      1000000
#define NQ      500000
#define NDST_ALL (N_MRNA + N_SRNA)   // 120000 combined dst nodes (mrna first, then srna)

// Buckets: mrna dsts in 512-wide buckets, srna dsts in 128-wide buckets
// (balances edges/bucket: mrna deg~10 -> ~5.1K, srna deg~50 -> ~6.4K)
#define NB_M 196                      // 100000 / 512 rounded up
#define NB_S 157                      // 20000 / 128 rounded up
#define NB   (NB_M + NB_S)            // 353

typedef __attribute__((ext_vector_type(8))) short bf16x8;
typedef __attribute__((ext_vector_type(4))) float f32x4;

__device__ __forceinline__ unsigned short f2bf(float f) {
    unsigned int u = __float_as_uint(f);
    unsigned int r = (u + 0x7fffu + ((u >> 16) & 1u)) >> 16;   // RNE
    return (unsigned short)r;
}
__device__ __forceinline__ float bf2f(unsigned short h) {
    return __uint_as_float((unsigned int)h << 16);
}

// ---------------------------------------------------------------------------
// Bucketed CSR build (4 kernels). Records pack (ldst<<17)|src : src<2^17,
// ldst<2^9. All heavy writes land in L2-resident windows (no 16x line
// amplification like the old random scatter).
// ---------------------------------------------------------------------------

// 1) per-block LDS bucket histogram -> <=NB global atomics per block
__global__ __launch_bounds__(256) void k_bhist(const int* __restrict__ dst_sm,
                                               const int* __restrict__ dst_ms,
                                               int* __restrict__ bcnt) {
    __shared__ int lh[NB];
    for (int i = threadIdx.x; i < NB; i += 256) lh[i] = 0;
    __syncthreads();
    int i0 = blockIdx.x * 4096;
#pragma unroll
    for (int j = 0; j < 16; ++j) {
        int i = i0 + j * 256 + threadIdx.x;
        if (i < NE) {
            atomicAdd(&lh[dst_sm[i] >> 9], 1);
        } else if (i < 2 * NE) {
            atomicAdd(&lh[NB_M + (dst_ms[i - NE] >> 7)], 1);
        }
    }
    __syncthreads();
    for (int i = threadIdx.x; i < NB; i += 256)
        if (lh[i]) atomicAdd(&bcnt[i], lh[i]);
}

// 2) single-block scan of bucket counts -> bases + cursors; ptr tail
__global__ __launch_bounds__(512) void k_bscan(const int* __restrict__ bcnt,
                                               int* __restrict__ bbase,
                                               int* __restrict__ bcur,
                                               int* __restrict__ ptr_end) {
    __shared__ int s[512];
    int t = threadIdx.x;
    int v = (t < NB) ? bcnt[t] : 0;
    s[t] = v;
    __syncthreads();
    for (int off = 1; off < 512; off <<= 1) {
        int x = (t >= off) ? s[t - off] : 0;
        __syncthreads();
        s[t] += x;
        __syncthreads();
    }
    if (t < NB) { int ex = s[t] - v; bbase[t] = ex; bcur[t] = ex; }
    if (t == 0) { bbase[NB] = 2 * NE; *ptr_end = 2 * NE; }
}

// 3) bucket-binned record scatter: block reserves per-bucket runs, writes
//    records into sequential cursor windows (L2-combining writes).
__global__ __launch_bounds__(256) void k_bscatter(const int* __restrict__ src_sm,
                                                  const int* __restrict__ dst_sm,
                                                  const int* __restrict__ src_ms,
                                                  const int* __restrict__ dst_ms,
                                                  int* __restrict__ bcur,
                                                  unsigned int* __restrict__ recs) {
    __shared__ int lh[NB], gb[NB], lc[NB];
    int t = threadIdx.x;
    for (int i = t; i < NB; i += 256) { lh[i] = 0; lc[i] = 0; }
    __syncthreads();
    unsigned int rec[16];
    int bk[16];
    int i0 = blockIdx.x * 4096;
#pragma unroll
    for (int j = 0; j < 16; ++j) {
        int i = i0 + j * 256 + t;
        int b = -1; unsigned int r = 0;
        if (i < NE) {
            int d = dst_sm[i];
            b = d >> 9;
            r = ((unsigned int)(d - (b << 9)) << 17) | (unsigned int)src_sm[i];
        } else if (i < 2 * NE) {
            int jj = i - NE;
            int d = dst_ms[jj];
            int bs = d >> 7;
            b = NB_M + bs;
            r = ((unsigned int)(d - (bs << 7)) << 17) | (unsigned int)src_ms[jj];
        }
        bk[j] = b; rec[j] = r;
        if (b >= 0) atomicAdd(&lh[b], 1);
    }
    __syncthreads();
    for (int i = t; i < NB; i += 256)
        gb[i] = lh[i] ? atomicAdd(&bcur[i], lh[i]) : 0;
    __syncthreads();
#pragma unroll
    for (int j = 0; j < 16; ++j) {
        int b = bk[j];
        if (b >= 0) {
            int slot = atomicAdd(&lc[b], 1);
            recs[gb[b] + slot] = rec[j];
        }
    }
}

// 4) per-bucket CSR finalize: LDS dst histogram -> scan -> ptr (coalesced),
//    then place src into the bucket's contiguous col window.
__global__ __launch_bounds__(256) void k_bbuild(const unsigned int* __restrict__ recs,
                                                const int* __restrict__ bbase,
                                                int* __restrict__ ptr_all,
                                                int* __restrict__ col) {
    __shared__ int lh[512], lptr[512], lps[256];
    const int b = blockIdx.x, t = threadIdx.x;
    const int nd = (b < NB_M) ? min(512, N_MRNA - (b << 9))
                              : min(128, N_SRNA - ((b - NB_M) << 7));
    const int dst0 = (b < NB_M) ? (b << 9) : N_MRNA + ((b - NB_M) << 7);
    const int base = bbase[b];
    const int nbe = bbase[b + 1] - base;

    lh[t] = 0; lh[t + 256] = 0;
    __syncthreads();
    for (int e = t; e < nbe; e += 256)
        atomicAdd(&lh[recs[base + e] >> 17], 1);
    __syncthreads();

    // exclusive scan of lh[512] via 256 pair-partials
    int a0 = lh[2 * t], a1 = lh[2 * t + 1];
    int ps = a0 + a1;
    lps[t] = ps;
    __syncthreads();
    for (int off = 1; off < 256; off <<= 1) {
        int x = (t >= off) ? lps[t - off] : 0;
        __syncthreads();
        lps[t] += x;
        __syncthreads();
    }
    int ex = lps[t] - ps;
    lptr[2 * t] = ex;
    lptr[2 * t + 1] = ex + a0;
    __syncthreads();

    for (int d = t; d < nd; d += 256) ptr_all[dst0 + d] = base + lptr[d];

    // reuse lh as cursors starting at lptr
    lh[t] = lptr[t]; lh[t + 256] = lptr[t + 256];
    __syncthreads();
    for (int e = t; e < nbe; e += 256) {
        unsigned int r = recs[base + e];
        int slot = atomicAdd(&lh[r >> 17], 1);
        col[base + slot] = (int)(r & 0x1FFFFu);
    }
}

// ---------------------------------------------------------------------------
// fp32 -> bf16 conversion (vectorized, grid-stride)
// ---------------------------------------------------------------------------
__global__ __launch_bounds__(256) void k_cvt_bf(const float* __restrict__ src,
                                                unsigned short* __restrict__ dst, int n4) {
    int i = blockIdx.x * 256 + threadIdx.x;
    int stride = gridDim.x * 256;
    for (; i < n4; i += stride) {
        float4 v = ((const float4*)src)[i];
        unsigned int p0 = (unsigned int)f2bf(v.x) | ((unsigned int)f2bf(v.y) << 16);
        unsigned int p1 = (unsigned int)f2bf(v.z) | ((unsigned int)f2bf(v.w) << 16);
        ((uint2*)dst)[i] = make_uint2(p0, p1);
    }
}

// Build Wt[c][k] = bf16( k<128 ? Wl[k][c] : Wr[k-128][c] ), c in [0,128), k in [0,256)
__global__ __launch_bounds__(256) void k_build_wt(const float* __restrict__ Wl,
                                                  const float* __restrict__ Wr,
                                                  unsigned short* __restrict__ Wt) {
    int tid = blockIdx.x * 256 + threadIdx.x;   // 32768 threads
    int c = tid & 127, k = tid >> 7;
    float v = (k < 128) ? Wl[k * 128 + c] : Wr[(k - 128) * 128 + c];
    Wt[c * 256 + k] = f2bf(v);
}

// ---------------------------------------------------------------------------
// Segment mean over bf16 rows: one wave per dst row; lane holds 2 features.
// fp32 accumulate, bf16 output.
// ---------------------------------------------------------------------------
__global__ __launch_bounds__(256) void k_seg_mean_bf(const unsigned short* __restrict__ xsrc,
                                                     const int* __restrict__ rowptr,
                                                     const int* __restrict__ cols,
                                                     unsigned short* __restrict__ outm,
                                                     int ndst) {
    int wave = (blockIdx.x * 256 + threadIdx.x) >> 6;
    int lane = threadIdx.x & 63;
    if (wave >= ndst) return;
    int beg = rowptr[wave], end = rowptr[wave + 1];
    float a0x = 0.f, a0y = 0.f, a1x = 0.f, a1y = 0.f;
    float a2x = 0.f, a2y = 0.f, a3x = 0.f, a3y = 0.f;
    int e = beg;
    for (; e + 4 <= end; e += 4) {
        int s0 = cols[e], s1 = cols[e + 1], s2 = cols[e + 2], s3 = cols[e + 3];
        unsigned int v0 = ((const unsigned int*)(xsrc + (size_t)s0 * FDIM))[lane];
        unsigned int v1 = ((const unsigned int*)(xsrc + (size_t)s1 * FDIM))[lane];
        unsigned int v2 = ((const unsigned int*)(xsrc + (size_t)s2 * FDIM))[lane];
        unsigned int v3 = ((const unsigned int*)(xsrc + (size_t)s3 * FDIM))[lane];
        a0x += bf2f((unsigned short)v0); a0y += bf2f((unsigned short)(v0 >> 16));
        a1x += bf2f((unsigned short)v1); a1y += bf2f((unsigned short)(v1 >> 16));
        a2x += bf2f((unsigned short)v2); a2y += bf2f((unsigned short)(v2 >> 16));
        a3x += bf2f((unsigned short)v3); a3y += bf2f((unsigned short)(v3 >> 16));
    }
    for (; e < end; ++e) {
        unsigned int v = ((const unsigned int*)(xsrc + (size_t)cols[e] * FDIM))[lane];
        a0x += bf2f((unsigned short)v); a0y += bf2f((unsigned short)(v >> 16));
    }
    float inv = 1.0f / fmaxf((float)(end - beg), 1.0f);
    float ox = (a0x + a1x + a2x + a3x) * inv;
    float oy = (a0y + a1y + a2y + a3y) * inv;
    unsigned int packed = (unsigned int)f2bf(ox) | ((unsigned int)f2bf(oy) << 16);
    ((unsigned int*)(outm + (size_t)wave * FDIM))[lane] = packed;
}

// ---------------------------------------------------------------------------
// MFMA GEMM: out[n][128] = [A0 | A1] @ W (K=256 concat) + bias, optional ReLU.
// A0 = mean_bf [n][128] (k 0..127), A1 = xd_bf [n][128] (k 128..255).
// Wt[c][k] (= W[k][c]) staged to LDS with XOR swizzle. Block 128x128, 4 waves
// of 64x64 (4x4 frags of 16x16x32). In-place out==A0 is safe.
// ---------------------------------------------------------------------------
template <bool RELU>
__global__ __launch_bounds__(256, 2) void k_gemm_mfma(const unsigned short* __restrict__ A0,
                                                      const unsigned short* __restrict__ A1,
                                                      const unsigned short* __restrict__ Wt,
                                                      const float* __restrict__ bias,
                                                      unsigned short* __restrict__ out,
                                                      int n) {
    __shared__ uint4 smem4[4352];            // 69632 B: 64KB W stage, reused as epilogue
    char* smem = (char*)smem4;

    const int t = threadIdx.x;
#pragma unroll
    for (int i = 0; i < 16; ++i) {
        int j = i * 256 + t;                 // 4096 chunks of 16B
        int byteo = j << 4;
        int c = byteo >> 9;
        int off = byteo & 511;
        int swz = off ^ ((c & 7) << 4);
        uint4 v = ((const uint4*)Wt)[j];
        *(uint4*)(smem + c * 512 + swz) = v;
    }
    __syncthreads();

    const int w = t >> 6, l = t & 63;
    const int wr = w >> 1, wc = w & 1;       // 2x2 wave grid
    const int rowbase = blockIdx.x * 128 + wr * 64;
    const int colbase = wc * 64;
    const int lr = l & 15;
    const int lk = (l >> 4) * 8;

    f32x4 acc[4][4];
#pragma unroll
    for (int a = 0; a < 4; ++a)
#pragma unroll
        for (int b = 0; b < 4; ++b)
#pragma unroll
            for (int e = 0; e < 4; ++e) acc[a][b][e] = 0.f;

    bf16x8 az;
#pragma unroll
    for (int e = 0; e < 8; ++e) az[e] = 0;

#pragma unroll
    for (int s = 0; s < 8; ++s) {
        const unsigned short* Abuf = (s < 4) ? A0 : A1;
        const int kk = (s & 3) * 32 + lk;
        bf16x8 afr[4];
#pragma unroll
        for (int af = 0; af < 4; ++af) {
            int row = rowbase + af * 16 + lr;
            afr[af] = (row < n) ? *(const bf16x8*)(Abuf + (size_t)row * FDIM + kk) : az;
        }
        bf16x8 bfr[4];
#pragma unroll
        for (int bf = 0; bf < 4; ++bf) {
            int c = colbase + bf * 16 + lr;
            int off = s * 64 + lk * 2;
            int swz = off ^ ((c & 7) << 4);
            bfr[bf] = *(const bf16x8*)(smem + c * 512 + swz);
        }
#pragma unroll
        for (int af = 0; af < 4; ++af)
#pragma unroll
            for (int bf = 0; bf < 4; ++bf)
                acc[af][bf] = __builtin_amdgcn_mfma_f32_16x16x32_bf16(afr[af], bfr[bf],
                                                                      acc[af][bf], 0, 0, 0);
    }

    __syncthreads();
    float* sD = (float*)(smem + w * 17408);  // 64 x 68 fp32 per wave

#pragma unroll
    for (int af = 0; af < 4; ++af)
#pragma unroll
        for (int bf = 0; bf < 4; ++bf)
#pragma unroll
            for (int r = 0; r < 4; ++r)
                sD[(af * 16 + (l >> 4) * 4 + r) * 68 + bf * 16 + lr] = acc[af][bf][r];

#pragma unroll
    for (int j = 0; j < 8; ++j) {
        int flat = j * 512 + l * 8;
        int row = flat >> 6;
        int c0 = flat & 63;
        int grow = rowbase + row;
        if (grow >= n) continue;
        float4 v0 = *(float4*)(&sD[row * 68 + c0]);
        float4 v1 = *(float4*)(&sD[row * 68 + c0 + 4]);
        int gc = colbase + c0;
        float4 b0 = *(const float4*)(bias + gc);
        float4 b1 = *(const float4*)(bias + gc + 4);
        float o[8] = {v0.x + b0.x, v0.y + b0.y, v0.z + b0.z, v0.w + b0.w,
                      v1.x + b1.x, v1.y + b1.y, v1.z + b1.z, v1.w + b1.w};
        if (RELU) {
#pragma unroll
            for (int e = 0; e < 8; ++e) o[e] = fmaxf(o[e], 0.f);
        }
        uint4 pv;
        pv.x = (unsigned int)f2bf(o[0]) | ((unsigned int)f2bf(o[1]) << 16);
        pv.y = (unsigned int)f2bf(o[2]) | ((unsigned int)f2bf(o[3]) << 16);
        pv.z = (unsigned int)f2bf(o[4]) | ((unsigned int)f2bf(o[5]) << 16);
        pv.w = (unsigned int)f2bf(o[6]) | ((unsigned int)f2bf(o[7]) << 16);
        *(uint4*)(out + (size_t)grow * FDIM + gc) = pv;
    }
}

// ---------------------------------------------------------------------------
// Decoder: out[q] = dot(zS[row[q]], zM[col[q]]) over bf16 rows; wave per query.
// ---------------------------------------------------------------------------
__global__ __launch_bounds__(256) void k_decoder_bf(const unsigned short* __restrict__ zS,
                                                    const unsigned short* __restrict__ zM,
                                                    const int* __restrict__ rows,
                                                    const int* __restrict__ cols,
                                                    float* __restrict__ out) {
    int w = (blockIdx.x * 256 + threadIdx.x) >> 6;
    int lane = threadIdx.x & 63;
    if (w >= NQ) return;
    int r = rows[w], c = cols[w];
    unsigned int va = ((const unsigned int*)(zS + (size_t)r * FDIM))[lane];
    unsigned int vb = ((const unsigned int*)(zM + (size_t)c * FDIM))[lane];
    float s = bf2f((unsigned short)va) * bf2f((unsigned short)vb) +
              bf2f((unsigned short)(va >> 16)) * bf2f((unsigned short)(vb >> 16));
    for (int off = 32; off; off >>= 1) s += __shfl_down(s, off);
    if (lane == 0) out[w] = s;
}

// ---------------------------------------------------------------------------
// Launch
// ---------------------------------------------------------------------------
extern "C" void kernel_launch(void* const* d_in, const int* in_sizes, int n_in,
                              void* d_out, int out_size, void* d_ws, size_t ws_size,
                              hipStream_t stream) {
    const float* x_srna = (const float*)d_in[0];
    const float* x_mrna = (const float*)d_in[1];
    const int* src_sm = (const int*)d_in[2];
    const int* dst_sm = (const int*)d_in[3];
    const int* src_ms = (const int*)d_in[4];
    const int* dst_ms = (const int*)d_in[5];
    const int* lbl_row = (const int*)d_in[6];
    const int* lbl_col = (const int*)d_in[7];
    const float* W1l_sm = (const float*)d_in[8];
    const float* W1r_sm = (const float*)d_in[9];
    const float* W1l_ms = (const float*)d_in[10];
    const float* W1r_ms = (const float*)d_in[11];
    const float* W2l_sm = (const float*)d_in[12];
    const float* W2r_sm = (const float*)d_in[13];
    const float* W2l_ms = (const float*)d_in[14];
    const float* W2r_ms = (const float*)d_in[15];
    const float* b1_sm = (const float*)d_in[16];
    const float* b1_ms = (const float*)d_in[17];
    const float* b2_sm = (const float*)d_in[18];
    const float* b2_ms = (const float*)d_in[19];
    float* out = (float*)d_out;

    // Workspace layout (16B aligned)
    char* ws = (char*)d_ws;
    unsigned short* xS_bf   = (unsigned short*)(ws + 0);          //  5,120,000
    unsigned short* xM_bf   = (unsigned short*)(ws + 5120000);    // 25,600,000
    unsigned short* meanM   = (unsigned short*)(ws + 30720000);   // 25,600,000 (becomes zM)
    unsigned short* meanS   = (unsigned short*)(ws + 56320000);   //  5,120,000 (becomes zS)
    unsigned short* hM_bf   = (unsigned short*)(ws + 61440000);   // 25,600,000
    unsigned short* hS_bf   = (unsigned short*)(ws + 87040000);   //  5,120,000
    unsigned short* Wt1sm   = (unsigned short*)(ws + 92160000);   //     65,536
    unsigned short* Wt1ms   = (unsigned short*)(ws + 92225536);   //     65,536
    unsigned short* Wt2sm   = (unsigned short*)(ws + 92291072);   //     65,536
    unsigned short* Wt2ms   = (unsigned short*)(ws + 92356608);   //     65,536
    int* ptr_all            = (int*)(ws + 92422144);              //    480,016 (120001 ints)
    int* col_all            = (int*)(ws + 92902160);              //  8,000,000
    unsigned int* recs      = (unsigned int*)(ws + 100902160);    //  8,000,000
    int* bcnt               = (int*)(ws + 108902160);             //      1,424
    int* bbase              = (int*)(ws + 108903584);             //      1,424 (NB+1 ints)
    int* bcur               = (int*)(ws + 108905008);             //      1,424
    // total ~108.9 MB

    // --- dtype prep (independent of CSR) ---
    k_cvt_bf<<<2048, 256, 0, stream>>>(x_srna, xS_bf, N_SRNA * FDIM / 4);
    k_cvt_bf<<<2048, 256, 0, stream>>>(x_mrna, xM_bf, N_MRNA * FDIM / 4);
    k_build_wt<<<128, 256, 0, stream>>>(W1l_sm, W1r_sm, Wt1sm);
    k_build_wt<<<128, 256, 0, stream>>>(W1l_ms, W1r_ms, Wt1ms);
    k_build_wt<<<128, 256, 0, stream>>>(W2l_sm, W2r_sm, Wt2sm);
    k_build_wt<<<128, 256, 0, stream>>>(W2l_ms, W2r_ms, Wt2ms);

    // --- Bucketed CSR build ---
    hipMemsetAsync(bcnt, 0, NB * sizeof(int), stream);
    const int nblk = (2 * NE + 4095) / 4096;               // 489
    k_bhist<<<nblk, 256, 0, stream>>>(dst_sm, dst_ms, bcnt);
    k_bscan<<<1, 512, 0, stream>>>(bcnt, bbase, bcur, &ptr_all[NDST_ALL]);
    k_bscatter<<<nblk, 256, 0, stream>>>(src_sm, dst_sm, src_ms, dst_ms, bcur, recs);
    k_bbuild<<<NB, 256, 0, stream>>>(recs, bbase, ptr_all, col_all);

    // --- Layer 1 ---
    k_seg_mean_bf<<<(N_MRNA + 3) / 4, 256, 0, stream>>>(xS_bf, ptr_all, col_all, meanM, N_MRNA);
    k_seg_mean_bf<<<(N_SRNA + 3) / 4, 256, 0, stream>>>(xM_bf, ptr_all + N_MRNA, col_all, meanS, N_SRNA);
    k_gemm_mfma<true><<<(N_MRNA + 127) / 128, 256, 0, stream>>>(meanM, xM_bf, Wt1sm, b1_sm,
                                                                hM_bf, N_MRNA);
    k_gemm_mfma<true><<<(N_SRNA + 127) / 128, 256, 0, stream>>>(meanS, xS_bf, Wt1ms, b1_ms,
                                                                hS_bf, N_SRNA);

    // --- Layer 2 (z overwrites mean buffers in place) ---
    k_seg_mean_bf<<<(N_MRNA + 3) / 4, 256, 0, stream>>>(hS_bf, ptr_all, col_all, meanM, N_MRNA);
    k_seg_mean_bf<<<(N_SRNA + 3) / 4, 256, 0, stream>>>(hM_bf, ptr_all + N_MRNA, col_all, meanS, N_SRNA);
    k_gemm_mfma<false><<<(N_MRNA + 127) / 128, 256, 0, stream>>>(meanM, hM_bf, Wt2sm, b2_sm,
                                                                 meanM, N_MRNA);
    k_gemm_mfma<false><<<(N_SRNA + 127) / 128, 256, 0, stream>>>(meanS, hS_bf, Wt2ms, b2_ms,
                                                                 meanS, N_SRNA);

    // --- Decoder ---
    k_decoder_bf<<<(NQ + 3) / 4, 256, 0, stream>>>(meanS, meanM, lbl_row, lbl_col, out);
}